// Round 3
// baseline (128.488 us; speedup 1.0000x reference)
//
#include <hip/hip_runtime.h>

#define DM 512
#define DI 1024
#define MM 16

typedef __attribute__((ext_vector_type(4))) float f32x4;
typedef __attribute__((ext_vector_type(8))) short short8;
typedef __attribute__((ext_vector_type(8))) unsigned short ushort8;

__device__ __forceinline__ unsigned short f2bf(float x) {
  union { float f; unsigned u; } c; c.f = x;
  unsigned r = (c.u + 0x7fffu + ((c.u >> 16) & 1u)) >> 16;
  return (unsigned short)r;
}
__device__ __forceinline__ float bf2f(unsigned short h) {
  union { unsigned u; float f; } c; c.u = ((unsigned)h) << 16; return c.f;
}

__device__ __forceinline__ void gload_lds16(const void* g, void* l) {
  __builtin_amdgcn_global_load_lds(
      (const __attribute__((address_space(1))) unsigned int*)g,
      (__attribute__((address_space(3))) unsigned int*)l, 16, 0, 0);
}

// ---- weight transposes: W [K][N] f32 -> Wt [N][K] bf16 (3 weights, 1 launch)
__device__ __forceinline__ void wt_tile(const float* __restrict__ W,
                                        unsigned short* __restrict__ Wt,
                                        int K, int N, int bx, int by,
                                        float (*tile)[33], int tx, int ty) {
  #pragma unroll
  for (int i = ty; i < 32; i += 8)
    tile[i][tx] = W[(size_t)(by + i) * N + bx + tx];
  __syncthreads();
  #pragma unroll
  for (int i = ty; i < 32; i += 8)
    Wt[(size_t)(bx + i) * K + by + tx] = f2bf(tile[tx][i]);
}

__global__ __launch_bounds__(256)
void wt_kernel(const float* __restrict__ W_in, const float* __restrict__ W_h,
               const float* __restrict__ W_out,
               unsigned short* __restrict__ Wt_in, unsigned short* __restrict__ Wt_h,
               unsigned short* __restrict__ Wt_out) {
  __shared__ float tile[32][33];
  const int b = blockIdx.x;
  const int tx = threadIdx.x & 31, ty = threadIdx.x >> 5;
  if (b < 1024)      wt_tile(W_in,  Wt_in,  1024, 1024, (b & 31) * 32, (b >> 5) * 32, tile, tx, ty);
  else if (b < 2048) { int lb = b - 1024; wt_tile(W_h,  Wt_h,  1024, 1024, (lb & 31) * 32, (lb >> 5) * 32, tile, tx, ty); }
  else               { int lb = b - 2048; wt_tile(W_out, Wt_out, 1024, 512, (lb & 15) * 32, (lb >> 4) * 32, tile, tx, ty); }
}

// ---- fused: gather (BW-bound) || GEMM1a = a @ W_in[:512] (compute, hidden
// ---- in the gather's memory shadow). 1:4 block interleave. No cross-block deps.
__global__ __launch_bounds__(256, 2)
void fused_kernel(const float* __restrict__ Aemb,
                  const float* __restrict__ Bemb,
                  const int* __restrict__ midx,
                  const unsigned short* __restrict__ Wt_in,
                  unsigned short* __restrict__ Xb,
                  unsigned short* __restrict__ H1accb,
                  int* __restrict__ counts) {
  __shared__ __align__(16) unsigned short As[128 * 64];
  __shared__ __align__(16) unsigned short Bs[128 * 64];
  const int b = blockIdx.x;
  const int t = threadIdx.x;

  if (b % 5 != 0) {
    // ---- gather path: masked mean of b-rows -> Xb [8192][512] bf16 + counts
    int gid = b - b / 5 - 1;
    int row = gid * 4 + (t >> 6);
    int l = t & 63;
    float acc[8] = {0,0,0,0,0,0,0,0};
    int cnt = 0;
    const int* ip = midx + row * MM;
    #pragma unroll
    for (int m = 0; m < MM; ++m) {
      int id = ip[m];
      if (id >= 0) {
        ++cnt;
        const f32x4* p = (const f32x4*)(Bemb + (size_t)id * DM) + l * 2;
        f32x4 u = p[0], v = p[1];
        acc[0]+=u[0]; acc[1]+=u[1]; acc[2]+=u[2]; acc[3]+=u[3];
        acc[4]+=v[0]; acc[5]+=v[1]; acc[6]+=v[2]; acc[7]+=v[3];
      }
    }
    float inv = 1.0f / (float)(cnt > 0 ? cnt : 1);
    ushort8 vb;
    #pragma unroll
    for (int i = 0; i < 8; ++i) vb[i] = f2bf(acc[i] * inv);
    *(ushort8*)(Xb + (size_t)row * DM + l * 8) = vb;
    if (l == 0) counts[row] = cnt;
    return;
  }

  // ---- GEMM1a path: H1accb[128x128 tile] = bf16( a[blockM..][0:512] @ Wt_in[blockN..][0:512]^T )
  const int id = b / 5;
  const int l = t & 63, w = t >> 6;
  const int wr = w >> 1, wc = w & 1;
  const int swzid = (id & 7) * 64 + (id >> 3);   // T1 chunked swizzle, nwg=512
  const int bx = swzid & 7, by = swzid >> 3;
  const int blockM = by * 128, blockN = bx * 128;
  const unsigned short* Bb = Wt_in + (size_t)blockN * 1024;

  f32x4 acc[4][4];
  #pragma unroll
  for (int m = 0; m < 4; ++m)
    #pragma unroll
    for (int n = 0; n < 4; ++n) acc[m][n] = (f32x4){0.f, 0.f, 0.f, 0.f};

  int so_row[4], so_col[4];
  #pragma unroll
  for (int c = 0; c < 4; ++c) {
    int o = c * 4096 + t * 16;
    int row = o >> 7;
    int cb = (o & 127) ^ ((row & 7) << 4);
    so_row[c] = row; so_col[c] = cb >> 1;
  }

  const int r = l & 15, ko = (l >> 4) * 8;
  const int swz = (r & 7) << 4;
  const char* Ac = (const char*)As;
  const char* Bc = (const char*)Bs;

  // A reg-staged: f32 global -> cvt bf16 -> swizzled ds_write (source linear,
  // write+read both swizzled: both-sides rule).
  #define STAGE_A(K0)                                                         \
    _Pragma("unroll")                                                         \
    for (int c = 0; c < 4; ++c) {                                             \
      int o = c * 2048 + t * 8; int row = o >> 6, col = o & 63;               \
      const float* src = Aemb + (size_t)(blockM + row) * 512 + (K0) + col;    \
      f32x4 u = *(const f32x4*)src; f32x4 v = *(const f32x4*)(src + 4);       \
      ushort8 wv;                                                             \
      wv[0]=f2bf(u[0]); wv[1]=f2bf(u[1]); wv[2]=f2bf(u[2]); wv[3]=f2bf(u[3]); \
      wv[4]=f2bf(v[0]); wv[5]=f2bf(v[1]); wv[6]=f2bf(v[2]); wv[7]=f2bf(v[3]); \
      int lb = (row * 128 + col * 2) ^ ((row & 7) << 4);                      \
      *(ushort8*)((char*)As + lb) = wv;                                       \
    }
  #define STAGE_B(K0)                                                         \
    _Pragma("unroll")                                                         \
    for (int c = 0; c < 4; ++c)                                               \
      gload_lds16(Bb + (size_t)so_row[c] * 1024 + (K0) + so_col[c],           \
                  (char*)Bs + c * 4096 + w * 1024);

  STAGE_A(0)
  STAGE_B(0)
  for (int kt = 0; kt < 8; ++kt) {
    __syncthreads();
    #pragma unroll
    for (int kk = 0; kk < 64; kk += 32) {
      short8 aF[4], bF[4];
      #pragma unroll
      for (int m = 0; m < 4; ++m)
        aF[m] = *(const short8*)(Ac + (((wr * 64 + m * 16 + r) * 128 + (kk + ko) * 2) ^ swz));
      #pragma unroll
      for (int n = 0; n < 4; ++n)
        bF[n] = *(const short8*)(Bc + (((wc * 64 + n * 16 + r) * 128 + (kk + ko) * 2) ^ swz));
      #pragma unroll
      for (int m = 0; m < 4; ++m)
        #pragma unroll
        for (int n = 0; n < 4; ++n)
          acc[m][n] = __builtin_amdgcn_mfma_f32_16x16x32_bf16(aF[m], bF[n], acc[m][n], 0, 0, 0);
    }
    __syncthreads();
    if (kt < 7) {
      int k0 = (kt + 1) << 6;
      STAGE_A(k0)
      STAGE_B(k0)
    }
  }
  const int rowBase = blockM + wr * 64 + (l >> 4) * 4;
  #pragma unroll
  for (int m = 0; m < 4; ++m)
    #pragma unroll
    for (int j = 0; j < 4; ++j) {
      int grow = rowBase + m * 16 + j;
      #pragma unroll
      for (int n = 0; n < 4; ++n)
        H1accb[(size_t)grow * 1024 + blockN + wc * 64 + n * 16 + r] = f2bf(acc[m][n][j]);
    }
  #undef STAGE_A
  #undef STAGE_B
}

// ---- fallback full build_x (R1/R2-proven path; used only if ws too small)
__global__ void build_x_full(const float* __restrict__ Aemb,
                             const float* __restrict__ Bemb,
                             const int* __restrict__ midx,
                             unsigned short* __restrict__ X,
                             int* __restrict__ counts) {
  int row = blockIdx.x * 4 + (threadIdx.x >> 6);
  int l = threadIdx.x & 63;
  float acc[8] = {0,0,0,0,0,0,0,0};
  int cnt = 0;
  const int* ip = midx + row * MM;
  #pragma unroll
  for (int m = 0; m < MM; ++m) {
    int id = ip[m];
    if (id >= 0) {
      ++cnt;
      const f32x4* p = (const f32x4*)(Bemb + (size_t)id * DM) + l * 2;
      f32x4 u = p[0], v = p[1];
      acc[0]+=u[0]; acc[1]+=u[1]; acc[2]+=u[2]; acc[3]+=u[3];
      acc[4]+=v[0]; acc[5]+=v[1]; acc[6]+=v[2]; acc[7]+=v[3];
    }
  }
  float inv = 1.0f / (float)(cnt > 0 ? cnt : 1);
  const f32x4* pa = (const f32x4*)(Aemb + (size_t)row * DM) + l * 2;
  f32x4 a0 = pa[0], a1 = pa[1];
  ushort8 va, vb;
  va[0]=f2bf(a0[0]); va[1]=f2bf(a0[1]); va[2]=f2bf(a0[2]); va[3]=f2bf(a0[3]);
  va[4]=f2bf(a1[0]); va[5]=f2bf(a1[1]); va[6]=f2bf(a1[2]); va[7]=f2bf(a1[3]);
  #pragma unroll
  for (int i = 0; i < 8; ++i) vb[i] = f2bf(acc[i] * inv);
  *(ushort8*)(X + (size_t)row * DI + l * 8) = va;
  *(ushort8*)(X + (size_t)row * DI + DM + l * 8) = vb;
  if (l == 0) counts[row] = cnt;
}

// ---- generalized GEMM: C = act(A[M][Kext](lda) @ Bt[N][Kext](ldb)^T [+Cadd] + bias)
template<int RELU, int FINAL, int ADDC>
__global__ __launch_bounds__(256, 2)
void gemm_kernel(const unsigned short* __restrict__ A, int lda,
                 const unsigned short* __restrict__ Bt, int ldb, int Kext,
                 const float* __restrict__ bias,
                 const unsigned short* __restrict__ Cadd,
                 unsigned short* __restrict__ Cb,
                 float* __restrict__ Cf,
                 const int* __restrict__ counts,
                 int N) {
  __shared__ __align__(16) unsigned short As[128 * 64];
  __shared__ __align__(16) unsigned short Bs[128 * 64];
  const int t = threadIdx.x;
  const int l = t & 63, w = t >> 6;
  const int wr = w >> 1, wc = w & 1;

  const int nwg = gridDim.x * gridDim.y;
  const int wg = blockIdx.y * gridDim.x + blockIdx.x;
  const int swzid = (wg & 7) * (nwg >> 3) + (wg >> 3);
  const int bx = swzid % gridDim.x, by = swzid / gridDim.x;

  const int blockM = by * 128, blockN = bx * 128;
  const unsigned short* Ab = A + (size_t)blockM * lda;
  const unsigned short* Bb = Bt + (size_t)blockN * ldb;

  f32x4 acc[4][4];
  #pragma unroll
  for (int m = 0; m < 4; ++m)
    #pragma unroll
    for (int n = 0; n < 4; ++n) acc[m][n] = (f32x4){0.f, 0.f, 0.f, 0.f};

  int so_row[4], so_col[4];
  #pragma unroll
  for (int c = 0; c < 4; ++c) {
    int o = c * 4096 + t * 16;
    int row = o >> 7;
    int cb = (o & 127) ^ ((row & 7) << 4);
    so_row[c] = row; so_col[c] = cb >> 1;
  }

  const int r = l & 15, ko = (l >> 4) * 8;
  const int swz = (r & 7) << 4;
  const char* Ac = (const char*)As;
  const char* Bc = (const char*)Bs;
  const int NT = Kext >> 6;

  #pragma unroll
  for (int c = 0; c < 4; ++c) {
    gload_lds16(Ab + (size_t)so_row[c] * lda + so_col[c], (char*)As + c * 4096 + w * 1024);
    gload_lds16(Bb + (size_t)so_row[c] * ldb + so_col[c], (char*)Bs + c * 4096 + w * 1024);
  }

  for (int kt = 0; kt < NT; ++kt) {
    __syncthreads();
    #pragma unroll
    for (int kk = 0; kk < 64; kk += 32) {
      short8 aF[4], bF[4];
      #pragma unroll
      for (int m = 0; m < 4; ++m)
        aF[m] = *(const short8*)(Ac + (((wr * 64 + m * 16 + r) * 128 + (kk + ko) * 2) ^ swz));
      #pragma unroll
      for (int n = 0; n < 4; ++n)
        bF[n] = *(const short8*)(Bc + (((wc * 64 + n * 16 + r) * 128 + (kk + ko) * 2) ^ swz));
      #pragma unroll
      for (int m = 0; m < 4; ++m)
        #pragma unroll
        for (int n = 0; n < 4; ++n)
          acc[m][n] = __builtin_amdgcn_mfma_f32_16x16x32_bf16(aF[m], bF[n], acc[m][n], 0, 0, 0);
    }
    __syncthreads();
    if (kt + 1 < NT) {
      int k0 = (kt + 1) << 6;
      #pragma unroll
      for (int c = 0; c < 4; ++c) {
        gload_lds16(Ab + (size_t)so_row[c] * lda + k0 + so_col[c], (char*)As + c * 4096 + w * 1024);
        gload_lds16(Bb + (size_t)so_row[c] * ldb + k0 + so_col[c], (char*)Bs + c * 4096 + w * 1024);
      }
    }
  }

  float bn[4];
  #pragma unroll
  for (int n = 0; n < 4; ++n) bn[n] = bias[blockN + wc * 64 + n * 16 + r];
  const int rowBase = blockM + wr * 64 + (l >> 4) * 4;
  #pragma unroll
  for (int m = 0; m < 4; ++m) {
    #pragma unroll
    for (int j = 0; j < 4; ++j) {
      int grow = rowBase + m * 16 + j;
      if (FINAL) {
        float cm = (counts[grow] > 0) ? 1.0f : 0.0f;
        #pragma unroll
        for (int n = 0; n < 4; ++n) {
          float v = (acc[m][n][j] + bn[n]) * cm;
          Cf[(size_t)grow * N + blockN + wc * 64 + n * 16 + r] = v;
        }
      } else {
        #pragma unroll
        for (int n = 0; n < 4; ++n) {
          int gcol = blockN + wc * 64 + n * 16 + r;
          float v = acc[m][n][j] + bn[n];
          if (ADDC) v += bf2f(Cadd[(size_t)grow * N + gcol]);
          if (RELU) v = v > 0.f ? v : 0.f;
          Cb[(size_t)grow * N + gcol] = f2bf(v);
        }
      }
    }
  }
}

extern "C" void kernel_launch(void* const* d_in, const int* in_sizes, int n_in,
                              void* d_out, int out_size, void* d_ws, size_t ws_size,
                              hipStream_t stream) {
  const float* a_emb = (const float*)d_in[0];
  const float* b_emb = (const float*)d_in[1];
  const int*   midx  = (const int*)d_in[2];
  const float* W_in  = (const float*)d_in[3];
  const float* b_in  = (const float*)d_in[4];
  const float* W_h   = (const float*)d_in[5];
  const float* b_h   = (const float*)d_in[6];
  const float* W_out = (const float*)d_in[7];
  const float* b_out = (const float*)d_in[8];
  char* ws = (char*)d_ws;

  if (ws_size >= 47218688ull) {
    // overlap pipeline
    unsigned short* Xb     = (unsigned short*)(ws);              //  8 MiB [0,8M)
    unsigned short* H1accb = (unsigned short*)(ws + 8388608);    // 16 MiB [8M,24M)
    unsigned short* H1     = (unsigned short*)(ws + 25165824);   // 16 MiB [24M,40M)
    unsigned short* H2     = (unsigned short*)(ws);              // 16 MiB, reuses [0,16M) after G1b
    unsigned short* Wt_in  = (unsigned short*)(ws + 41943040);   //  2 MiB
    unsigned short* Wt_h   = (unsigned short*)(ws + 44040192);   //  2 MiB
    unsigned short* Wt_out = (unsigned short*)(ws + 46137344);   //  1 MiB
    int*            counts = (int*)(ws + 47185920);              // 32 KiB

    wt_kernel<<<2560, 256, 0, stream>>>(W_in, W_h, W_out, Wt_in, Wt_h, Wt_out);
    fused_kernel<<<2560, 256, 0, stream>>>(a_emb, b_emb, midx, Wt_in, Xb, H1accb, counts);
    gemm_kernel<1, 0, 1><<<dim3(8, 64), 256, 0, stream>>>(Xb, 512, Wt_in + 512, 1024, 512,
                                                          b_in, H1accb, H1, nullptr, nullptr, 1024);
    gemm_kernel<1, 0, 0><<<dim3(8, 64), 256, 0, stream>>>(H1, 1024, Wt_h, 1024, 1024,
                                                          b_h, nullptr, H2, nullptr, nullptr, 1024);
    gemm_kernel<0, 1, 0><<<dim3(4, 64), 256, 0, stream>>>(H2, 1024, Wt_out, 1024, 1024,
                                                          b_out, nullptr, nullptr, (float*)d_out, counts, 512);
  } else {
    // proven R2 pipeline (ws too small for overlap buffers)
    unsigned short* X      = (unsigned short*)(ws);              // 16 MiB (reused as H2)
    unsigned short* H1     = (unsigned short*)(ws + 16777216);   // 16 MiB
    unsigned short* Wt_in  = (unsigned short*)(ws + 33554432);
    unsigned short* Wt_h   = (unsigned short*)(ws + 35651584);
    unsigned short* Wt_out = (unsigned short*)(ws + 37748736);
    int*            counts = (int*)(ws + 38797312);

    wt_kernel<<<2560, 256, 0, stream>>>(W_in, W_h, W_out, Wt_in, Wt_h, Wt_out);
    build_x_full<<<2048, 256, 0, stream>>>(a_emb, b_emb, midx, X, counts);
    gemm_kernel<1, 0, 0><<<dim3(8, 64), 256, 0, stream>>>(X, 1024, Wt_in, 1024, 1024,
                                                          b_in, nullptr, H1, nullptr, nullptr, 1024);
    gemm_kernel<1, 0, 0><<<dim3(8, 64), 256, 0, stream>>>(H1, 1024, Wt_h, 1024, 1024,
                                                          b_h, nullptr, X, nullptr, nullptr, 1024);
    gemm_kernel<0, 1, 0><<<dim3(4, 64), 256, 0, stream>>>(X, 1024, Wt_out, 1024, 1024,
                                                          b_out, nullptr, nullptr, (float*)d_out, counts, 512);
  }
}

// Round 4
// 117.732 us; speedup vs baseline: 1.0914x; 1.0914x over previous
//
#include <hip/hip_runtime.h>

#define DM 512
#define DI 1024
#define MM 16

typedef __attribute__((ext_vector_type(4))) float f32x4;
typedef __attribute__((ext_vector_type(8))) short short8;
typedef __attribute__((ext_vector_type(8))) unsigned short ushort8;

__device__ __forceinline__ unsigned short f2bf(float x) {
  union { float f; unsigned u; } c; c.f = x;
  unsigned r = (c.u + 0x7fffu + ((c.u >> 16) & 1u)) >> 16;
  return (unsigned short)r;
}
__device__ __forceinline__ float bf2f(unsigned short h) {
  union { unsigned u; float f; } c; c.u = ((unsigned)h) << 16; return c.f;
}

__device__ __forceinline__ void gload_lds16(const void* g, void* l) {
  __builtin_amdgcn_global_load_lds(
      (const __attribute__((address_space(1))) unsigned int*)g,
      (__attribute__((address_space(3))) unsigned int*)l, 16, 0, 0);
}

// ---- weight transposes: W [K][N] f32 -> Wt [N][K] bf16 (3 weights, 1 launch)
__device__ __forceinline__ void wt_tile(const float* __restrict__ W,
                                        unsigned short* __restrict__ Wt,
                                        int K, int N, int bx, int by,
                                        float (*tile)[33], int tx, int ty) {
  #pragma unroll
  for (int i = ty; i < 32; i += 8)
    tile[i][tx] = W[(size_t)(by + i) * N + bx + tx];
  __syncthreads();
  #pragma unroll
  for (int i = ty; i < 32; i += 8)
    Wt[(size_t)(bx + i) * K + by + tx] = f2bf(tile[tx][i]);
}

__global__ __launch_bounds__(256)
void wt_kernel(const float* __restrict__ W_in, const float* __restrict__ W_h,
               const float* __restrict__ W_out,
               unsigned short* __restrict__ Wt_in, unsigned short* __restrict__ Wt_h,
               unsigned short* __restrict__ Wt_out) {
  __shared__ float tile[32][33];
  const int b = blockIdx.x;
  const int tx = threadIdx.x & 31, ty = threadIdx.x >> 5;
  if (b < 1024)      wt_tile(W_in,  Wt_in,  1024, 1024, (b & 31) * 32, (b >> 5) * 32, tile, tx, ty);
  else if (b < 2048) { int lb = b - 1024; wt_tile(W_h,  Wt_h,  1024, 1024, (lb & 31) * 32, (lb >> 5) * 32, tile, tx, ty); }
  else               { int lb = b - 2048; wt_tile(W_out, Wt_out, 1024, 512, (lb & 15) * 32, (lb >> 4) * 32, tile, tx, ty); }
}

// ---- build_x: X = bf16(concat(a, masked_mean(b[idx]))); one wave per row (R2-proven)
__global__ void build_x_full(const float* __restrict__ Aemb,
                             const float* __restrict__ Bemb,
                             const int* __restrict__ midx,
                             unsigned short* __restrict__ X,
                             int* __restrict__ counts) {
  int row = blockIdx.x * 4 + (threadIdx.x >> 6);
  int l = threadIdx.x & 63;
  float acc[8] = {0,0,0,0,0,0,0,0};
  int cnt = 0;
  const int* ip = midx + row * MM;
  #pragma unroll
  for (int m = 0; m < MM; ++m) {
    int id = ip[m];
    if (id >= 0) {
      ++cnt;
      const f32x4* p = (const f32x4*)(Bemb + (size_t)id * DM) + l * 2;
      f32x4 u = p[0], v = p[1];
      acc[0]+=u[0]; acc[1]+=u[1]; acc[2]+=u[2]; acc[3]+=u[3];
      acc[4]+=v[0]; acc[5]+=v[1]; acc[6]+=v[2]; acc[7]+=v[3];
    }
  }
  float inv = 1.0f / (float)(cnt > 0 ? cnt : 1);
  const f32x4* pa = (const f32x4*)(Aemb + (size_t)row * DM) + l * 2;
  f32x4 a0 = pa[0], a1 = pa[1];
  ushort8 va, vb;
  va[0]=f2bf(a0[0]); va[1]=f2bf(a0[1]); va[2]=f2bf(a0[2]); va[3]=f2bf(a0[3]);
  va[4]=f2bf(a1[0]); va[5]=f2bf(a1[1]); va[6]=f2bf(a1[2]); va[7]=f2bf(a1[3]);
  #pragma unroll
  for (int i = 0; i < 8; ++i) vb[i] = f2bf(acc[i] * inv);
  *(ushort8*)(X + (size_t)row * DI + l * 8) = va;
  *(ushort8*)(X + (size_t)row * DI + DM + l * 8) = vb;
  if (l == 0) counts[row] = cnt;
}

// ---- deep-pipelined GEMM (T2+T3+T4+T5): C = relu(A[M][K] @ Bt[N][K]^T + bias)
// 256x128 tile, BK=64, 8 waves (4Mx2N), ring-3 LDS (144 KB), counted vmcnt(6),
// one barrier per K-tile, stage-before-ds_read, setprio around MFMA cluster.
// Grid MUST be dim3(8, M/256). Requires NT = K/64 >= 2.
template<int RELU>
__global__ __launch_bounds__(512, 2)
void gemm2_kernel(const unsigned short* __restrict__ A,
                  const unsigned short* __restrict__ Bt,
                  const float* __restrict__ bias,
                  unsigned short* __restrict__ C,
                  int N, int K) {
  extern __shared__ __align__(16) char smem[];
  // A bufs: smem + buf*32768 (3 x 32 KB); B bufs: smem + 98304 + buf*16384 (3 x 16 KB)
  const int t = threadIdx.x;               // 0..511
  const int l = t & 63, w = t >> 6;        // 8 waves
  const int wr = w >> 1, wc = w & 1;       // 4 x 2 wave grid

  // XCD swizzle for grid (8,32): XCD x = f&7 owns by in [x*4, x*4+4) x all bx
  // -> per-XCD working set = A-chunk 2 MB + full B 2 MB ~= 4 MB L2.
  const int f = blockIdx.y * gridDim.x + blockIdx.x;
  const int xcd = f & 7, j = f >> 3;
  const int bx = j & 7, by = xcd * 4 + (j >> 3);
  const int blockM = by * 256, blockN = bx * 128;
  const unsigned short* Ab = A + (size_t)blockM * K;
  const unsigned short* Bb = Bt + (size_t)blockN * K;

  f32x4 acc[4][4];
  #pragma unroll
  for (int m = 0; m < 4; ++m)
    #pragma unroll
    for (int n = 0; n < 4; ++n) acc[m][n] = (f32x4){0.f, 0.f, 0.f, 0.f};

  // staging offsets: linear LDS dest, inverse-swizzled global source column
  int arow[4], acol[4], brow[2], bcol[2];
  #pragma unroll
  for (int c = 0; c < 4; ++c) {
    int o = c * 8192 + t * 16;
    int row = o >> 7;
    int cb = (o & 127) ^ ((row & 7) << 4);
    arow[c] = row; acol[c] = cb >> 1;
  }
  #pragma unroll
  for (int c = 0; c < 2; ++c) {
    int o = c * 8192 + t * 16;
    int row = o >> 7;
    int cb = (o & 127) ^ ((row & 7) << 4);
    brow[c] = row; bcol[c] = cb >> 1;
  }

  const int r = l & 15, ko = (l >> 4) * 8;
  const int swz = (r & 7) << 4;
  const int NT = K >> 6;

  float bn[4];
  #pragma unroll
  for (int n = 0; n < 4; ++n) bn[n] = bias[blockN + wc * 64 + n * 16 + r];

  #define STAGE(BUF, KT)                                                      \
    {                                                                         \
      int k0_ = (KT) << 6;                                                    \
      char* ab_ = smem + (BUF) * 32768;                                       \
      char* bb_ = smem + 98304 + (BUF) * 16384;                               \
      _Pragma("unroll")                                                       \
      for (int c = 0; c < 4; ++c)                                             \
        gload_lds16(Ab + (size_t)arow[c] * K + k0_ + acol[c],                 \
                    ab_ + c * 8192 + t * 16);                                 \
      _Pragma("unroll")                                                       \
      for (int c = 0; c < 2; ++c)                                             \
        gload_lds16(Bb + (size_t)brow[c] * K + k0_ + bcol[c],                 \
                    bb_ + c * 8192 + t * 16);                                 \
    }

  STAGE(0, 0)
  STAGE(1, 1)

  int rc = 0;   // read buffer  = kt % 3
  int sc = 2;   // stage buffer = (kt+2) % 3
  for (int kt = 0; kt < NT; ++kt) {
    // wait for THIS tile's 6 loads; keep next tile's 6 in flight (T4 counted)
    if (kt + 1 < NT) { asm volatile("s_waitcnt vmcnt(6)" ::: "memory"); }
    else             { asm volatile("s_waitcnt vmcnt(0)" ::: "memory"); }
    __builtin_amdgcn_sched_barrier(0);
    __builtin_amdgcn_s_barrier();
    __builtin_amdgcn_sched_barrier(0);
    // stage tile kt+2 into buf (kt+2)%3 = (kt-1)%3 — its readers drained their
    // ds_reads (lgkmcnt(0)) before the barrier above. Issue BEFORE ds_read/MFMA.
    if (kt + 2 < NT) STAGE(sc, kt + 2)

    const char* Ac = smem + rc * 32768;
    const char* Bc = smem + 98304 + rc * 16384;
    short8 aF[2][4], bF[2][4];
    #pragma unroll
    for (int kk = 0; kk < 2; ++kk) {
      #pragma unroll
      for (int m = 0; m < 4; ++m)
        aF[kk][m] = *(const short8*)(Ac + (((wr * 64 + m * 16 + r) * 128 + (kk * 32 + ko) * 2) ^ swz));
      #pragma unroll
      for (int n = 0; n < 4; ++n)
        bF[kk][n] = *(const short8*)(Bc + (((wc * 64 + n * 16 + r) * 128 + (kk * 32 + ko) * 2) ^ swz));
    }
    asm volatile("s_waitcnt lgkmcnt(0)" ::: "memory");
    __builtin_amdgcn_sched_barrier(0);

    __builtin_amdgcn_s_setprio(1);
    #pragma unroll
    for (int kk = 0; kk < 2; ++kk)
      #pragma unroll
      for (int m = 0; m < 4; ++m)
        #pragma unroll
        for (int n = 0; n < 4; ++n)
          acc[m][n] = __builtin_amdgcn_mfma_f32_16x16x32_bf16(aF[kk][m], bF[kk][n], acc[m][n], 0, 0, 0);
    __builtin_amdgcn_s_setprio(0);

    rc = (rc == 2) ? 0 : rc + 1;
    sc = (sc == 2) ? 0 : sc + 1;
  }
  #undef STAGE

  const int rowBase = blockM + wr * 64 + (l >> 4) * 4;
  #pragma unroll
  for (int m = 0; m < 4; ++m)
    #pragma unroll
    for (int jj = 0; jj < 4; ++jj) {
      int grow = rowBase + m * 16 + jj;
      #pragma unroll
      for (int n = 0; n < 4; ++n) {
        float v = acc[m][n][jj] + bn[n];
        if (RELU) v = v > 0.f ? v : 0.f;
        C[(size_t)grow * N + blockN + wc * 64 + n * 16 + r] = f2bf(v);
      }
    }
}

// ---- m97-structure GEMM (proven) for the final layer (N=512, counts mask, f32 out)
template<int RELU, int FINAL>
__global__ __launch_bounds__(256, 2)
void gemm_kernel(const unsigned short* __restrict__ A, int lda,
                 const unsigned short* __restrict__ Bt, int ldb, int Kext,
                 const float* __restrict__ bias,
                 unsigned short* __restrict__ Cb,
                 float* __restrict__ Cf,
                 const int* __restrict__ counts,
                 int N) {
  __shared__ __align__(16) unsigned short As[128 * 64];
  __shared__ __align__(16) unsigned short Bs[128 * 64];
  const int t = threadIdx.x;
  const int l = t & 63, w = t >> 6;
  const int wr = w >> 1, wc = w & 1;

  const int nwg = gridDim.x * gridDim.y;
  const int wg = blockIdx.y * gridDim.x + blockIdx.x;
  const int swzid = (wg & 7) * (nwg >> 3) + (wg >> 3);
  const int bx = swzid % gridDim.x, by = swzid / gridDim.x;

  const int blockM = by * 128, blockN = bx * 128;
  const unsigned short* Ab = A + (size_t)blockM * lda;
  const unsigned short* Bb = Bt + (size_t)blockN * ldb;

  f32x4 acc[4][4];
  #pragma unroll
  for (int m = 0; m < 4; ++m)
    #pragma unroll
    for (int n = 0; n < 4; ++n) acc[m][n] = (f32x4){0.f, 0.f, 0.f, 0.f};

  int so_row[4], so_col[4];
  #pragma unroll
  for (int c = 0; c < 4; ++c) {
    int o = c * 4096 + t * 16;
    int row = o >> 7;
    int cb = (o & 127) ^ ((row & 7) << 4);
    so_row[c] = row; so_col[c] = cb >> 1;
  }

  const int r = l & 15, ko = (l >> 4) * 8;
  const int swz = (r & 7) << 4;
  const char* Ac = (const char*)As;
  const char* Bc = (const char*)Bs;
  const int NT = Kext >> 6;

  #pragma unroll
  for (int c = 0; c < 4; ++c) {
    gload_lds16(Ab + (size_t)so_row[c] * lda + so_col[c], (char*)As + c * 4096 + w * 1024);
    gload_lds16(Bb + (size_t)so_row[c] * ldb + so_col[c], (char*)Bs + c * 4096 + w * 1024);
  }

  for (int kt = 0; kt < NT; ++kt) {
    __syncthreads();
    #pragma unroll
    for (int kk = 0; kk < 64; kk += 32) {
      short8 aF[4], bF[4];
      #pragma unroll
      for (int m = 0; m < 4; ++m)
        aF[m] = *(const short8*)(Ac + (((wr * 64 + m * 16 + r) * 128 + (kk + ko) * 2) ^ swz));
      #pragma unroll
      for (int n = 0; n < 4; ++n)
        bF[n] = *(const short8*)(Bc + (((wc * 64 + n * 16 + r) * 128 + (kk + ko) * 2) ^ swz));
      #pragma unroll
      for (int m = 0; m < 4; ++m)
        #pragma unroll
        for (int n = 0; n < 4; ++n)
          acc[m][n] = __builtin_amdgcn_mfma_f32_16x16x32_bf16(aF[m], bF[n], acc[m][n], 0, 0, 0);
    }
    __syncthreads();
    if (kt + 1 < NT) {
      int k0 = (kt + 1) << 6;
      #pragma unroll
      for (int c = 0; c < 4; ++c) {
        gload_lds16(Ab + (size_t)so_row[c] * lda + k0 + so_col[c], (char*)As + c * 4096 + w * 1024);
        gload_lds16(Bb + (size_t)so_row[c] * ldb + k0 + so_col[c], (char*)Bs + c * 4096 + w * 1024);
      }
    }
  }

  float bn[4];
  #pragma unroll
  for (int n = 0; n < 4; ++n) bn[n] = bias[blockN + wc * 64 + n * 16 + r];
  const int rowBase = blockM + wr * 64 + (l >> 4) * 4;
  #pragma unroll
  for (int m = 0; m < 4; ++m) {
    #pragma unroll
    for (int jj = 0; jj < 4; ++jj) {
      int grow = rowBase + m * 16 + jj;
      if (FINAL) {
        float cm = (counts[grow] > 0) ? 1.0f : 0.0f;
        #pragma unroll
        for (int n = 0; n < 4; ++n) {
          float v = (acc[m][n][jj] + bn[n]) * cm;
          Cf[(size_t)grow * N + blockN + wc * 64 + n * 16 + r] = v;
        }
      } else {
        #pragma unroll
        for (int n = 0; n < 4; ++n) {
          float v = acc[m][n][jj] + bn[n];
          if (RELU) v = v > 0.f ? v : 0.f;
          Cb[(size_t)grow * N + blockN + wc * 64 + n * 16 + r] = f2bf(v);
        }
      }
    }
  }
}

extern "C" void kernel_launch(void* const* d_in, const int* in_sizes, int n_in,
                              void* d_out, int out_size, void* d_ws, size_t ws_size,
                              hipStream_t stream) {
  const float* a_emb = (const float*)d_in[0];
  const float* b_emb = (const float*)d_in[1];
  const int*   midx  = (const int*)d_in[2];
  const float* W_in  = (const float*)d_in[3];
  const float* b_in  = (const float*)d_in[4];
  const float* W_h   = (const float*)d_in[5];
  const float* b_h   = (const float*)d_in[6];
  const float* W_out = (const float*)d_in[7];
  const float* b_out = (const float*)d_in[8];
  char* ws = (char*)d_ws;

  unsigned short* X      = (unsigned short*)(ws);              // 16 MiB (reused as H2)
  unsigned short* H1     = (unsigned short*)(ws + 16777216);   // 16 MiB
  unsigned short* Wt_in  = (unsigned short*)(ws + 33554432);   //  2 MiB
  unsigned short* Wt_h   = (unsigned short*)(ws + 35651584);   //  2 MiB
  unsigned short* Wt_out = (unsigned short*)(ws + 37748736);   //  1 MiB
  int*            counts = (int*)(ws + 38797312);              // 32 KiB

  (void)hipFuncSetAttribute((const void*)gemm2_kernel<1>,
                            hipFuncAttributeMaxDynamicSharedMemorySize, 147456);

  wt_kernel<<<2560, 256, 0, stream>>>(W_in, W_h, W_out, Wt_in, Wt_h, Wt_out);
  build_x_full<<<2048, 256, 0, stream>>>(a_emb, b_emb, midx, X, counts);

  gemm2_kernel<1><<<dim3(8, 32), 512, 147456, stream>>>(X,  Wt_in, b_in, H1, 1024, 1024);
  gemm2_kernel<1><<<dim3(8, 32), 512, 147456, stream>>>(H1, Wt_h,  b_h,  X,  1024, 1024);
  gemm_kernel<0, 1><<<dim3(4, 64), 256, 0, stream>>>(X, 1024, Wt_out, 1024, 1024,
                                                     b_out, nullptr, (float*)d_out, counts, 512);
}

// Round 5
// 113.146 us; speedup vs baseline: 1.1356x; 1.0405x over previous
//
#include <hip/hip_runtime.h>

#define DM 512
#define DI 1024
#define MM 16

typedef __attribute__((ext_vector_type(4))) float f32x4;
typedef __attribute__((ext_vector_type(8))) short short8;
typedef __attribute__((ext_vector_type(8))) unsigned short ushort8;

__device__ __forceinline__ unsigned short f2bf(float x) {
  union { float f; unsigned u; } c; c.f = x;
  unsigned r = (c.u + 0x7fffu + ((c.u >> 16) & 1u)) >> 16;
  return (unsigned short)r;
}

__device__ __forceinline__ void gload_lds16(const void* g, void* l) {
  __builtin_amdgcn_global_load_lds(
      (const __attribute__((address_space(1))) unsigned int*)g,
      (__attribute__((address_space(3))) unsigned int*)l, 16, 0, 0);
}

// ---- fused prep (R2-proven): 3 weight transposes + build_x in one launch
__device__ __forceinline__ void wt_tile(const float* __restrict__ W,
                                        unsigned short* __restrict__ Wt,
                                        int K, int N, int bx, int by,
                                        float (*tile)[33], int tx, int ty) {
  #pragma unroll
  for (int i = ty; i < 32; i += 8)
    tile[i][tx] = W[(size_t)(by + i) * N + bx + tx];
  __syncthreads();
  #pragma unroll
  for (int i = ty; i < 32; i += 8)
    Wt[(size_t)(bx + i) * K + by + tx] = f2bf(tile[tx][i]);
}

__global__ __launch_bounds__(256)
void prep_kernel(const float* __restrict__ Aemb,
                 const float* __restrict__ Bemb,
                 const int* __restrict__ midx,
                 const float* __restrict__ W_in,
                 const float* __restrict__ W_h,
                 const float* __restrict__ W_out,
                 unsigned short* __restrict__ X,
                 int* __restrict__ counts,
                 unsigned short* __restrict__ Wt_in,
                 unsigned short* __restrict__ Wt_h,
                 unsigned short* __restrict__ Wt_out) {
  __shared__ float tile[32][33];
  const int b = blockIdx.x;
  const int tx = threadIdx.x & 31, ty = threadIdx.x >> 5;
  if (b < 1024) {
    wt_tile(W_in, Wt_in, 1024, 1024, (b & 31) * 32, (b >> 5) * 32, tile, tx, ty);
    return;
  } else if (b < 2048) {
    int lb = b - 1024;
    wt_tile(W_h, Wt_h, 1024, 1024, (lb & 31) * 32, (lb >> 5) * 32, tile, tx, ty);
    return;
  } else if (b < 2560) {
    int lb = b - 2048;
    wt_tile(W_out, Wt_out, 1024, 512, (lb & 15) * 32, (lb >> 4) * 32, tile, tx, ty);
    return;
  }
  int row = __builtin_amdgcn_readfirstlane((b - 2560) * 4 + (threadIdx.x >> 6));
  int l = threadIdx.x & 63;
  float acc[8] = {0,0,0,0,0,0,0,0};
  int cnt = 0;
  const int* ip = midx + row * MM;
  #pragma unroll
  for (int m = 0; m < MM; ++m) {
    int id = ip[m];
    if (id >= 0) {
      ++cnt;
      const f32x4* p = (const f32x4*)(Bemb + (size_t)id * DM) + l * 2;
      f32x4 u = p[0], v = p[1];
      acc[0]+=u[0]; acc[1]+=u[1]; acc[2]+=u[2]; acc[3]+=u[3];
      acc[4]+=v[0]; acc[5]+=v[1]; acc[6]+=v[2]; acc[7]+=v[3];
    }
  }
  float inv = 1.0f / (float)(cnt > 0 ? cnt : 1);
  const f32x4* pa = (const f32x4*)(Aemb + (size_t)row * DM) + l * 2;
  f32x4 a0 = pa[0], a1 = pa[1];
  ushort8 va, vb;
  va[0]=f2bf(a0[0]); va[1]=f2bf(a0[1]); va[2]=f2bf(a0[2]); va[3]=f2bf(a0[3]);
  va[4]=f2bf(a1[0]); va[5]=f2bf(a1[1]); va[6]=f2bf(a1[2]); va[7]=f2bf(a1[3]);
  #pragma unroll
  for (int i = 0; i < 8; ++i) vb[i] = f2bf(acc[i] * inv);
  *(ushort8*)(X + (size_t)row * DI + l * 8) = va;
  *(ushort8*)(X + (size_t)row * DI + DM + l * 8) = vb;
  if (l == 0) counts[row] = cnt;
}

// ---- fine-grained 2-phase-per-K-tile GEMM (T2+T3+T4+T5), fixed shape:
// C[8192][1024] = relu(A[8192][1024] @ Bt[1024][1024]^T + bias), all bf16 in.
// BM=256 BN=128 BK=64, 8 waves (2Mx4N), per-wave 128x32 (8Mx2N frags).
// LDS: 2 bufs x (A 32KB + B 16KB) = 96KB. NT=16.
// Sub-tile staging ledger (per thread, 6 loads/tile: A-qm0 2, B 2, A-qm1 2):
//   G(t).ph0 reads {A-qm0,B} of buf(t), stages (t+1).qm1;  end: vmcnt(6)
//   G(t).ph1 reads {A-qm1} of buf(t),  stages (t+2).qm0+B; end: vmcnt(6)
//   (epilogue: 6 -> 2 -> 0; prologue: 12 issued, vmcnt(8))
__global__ __launch_bounds__(512, 2)
void gemm8_kernel(const unsigned short* __restrict__ A,
                  const unsigned short* __restrict__ Bt,
                  const float* __restrict__ bias,
                  unsigned short* __restrict__ C) {
  extern __shared__ __align__(16) char smem[];
  const int t = threadIdx.x;
  const int l = t & 63, w = t >> 6;
  const int wr = w >> 2, wc = w & 3;            // 2M x 4N waves
  const int f = blockIdx.y * gridDim.x + blockIdx.x;   // grid (8,32), 256 blocks
  const int swzid = (f & 7) * 32 + (f >> 3);    // chunked XCD swizzle
  const int bx = swzid & 7, by = swzid >> 3;
  const int blockM = by * 256, blockN = bx * 128;
  const unsigned short* __restrict__ Ab = A + (size_t)blockM * 1024;
  const unsigned short* __restrict__ Bb = Bt + (size_t)blockN * 1024;
  const int r = l & 15, ko = (l >> 4) * 8;
  const int swz = (r & 7) << 4;
  const int strow = t >> 3;                                  // 0..63 in chunk
  const int stcolh = ((((t & 7) * 16) ^ ((strow & 7) << 4)) >> 1); // elem col

  f32x4 acc[8][2];
  #pragma unroll
  for (int m = 0; m < 8; ++m) {
    acc[m][0] = (f32x4){0.f,0.f,0.f,0.f};
    acc[m][1] = (f32x4){0.f,0.f,0.f,0.f};
  }

#define ST_A(BASE, KT, CH)                                                    \
  gload_lds16(Ab + (size_t)((CH)*64 + strow) * 1024 + ((KT)<<6) + stcolh,     \
              smem + (BASE) + (CH)*8192 + t*16);
#define ST_B(BASE, KT, CB)                                                    \
  gload_lds16(Bb + (size_t)((CB)*64 + strow) * 1024 + ((KT)<<6) + stcolh,     \
              smem + (BASE) + 32768 + (CB)*8192 + t*16);
#define ST_QM0B(BASE, KT) { ST_A(BASE,KT,0) ST_A(BASE,KT,2) ST_B(BASE,KT,0) ST_B(BASE,KT,1) }
#define ST_QM1(BASE, KT)  { ST_A(BASE,KT,1) ST_A(BASE,KT,3) }

#define WAIT_VM(N) { asm volatile("s_waitcnt vmcnt(" #N ")" ::: "memory");    \
                     __builtin_amdgcn_sched_barrier(0); }
#define WAIT_LGKM() { asm volatile("s_waitcnt lgkmcnt(0)" ::: "memory");      \
                      __builtin_amdgcn_sched_barrier(0); }
#define BAR() { __builtin_amdgcn_s_barrier();                                 \
                __builtin_amdgcn_sched_barrier(0); }

  short8 aF[4][2], bF[2][2];

#define LDA(MF4, KK, BASE, QM)                                                \
  aF[MF4][KK] = *(const short8*)(smem + (BASE) +                              \
      ((((wr*128 + ((QM)*4+(MF4))*16 + r) * 128) + ((KK)*32 + ko)*2) ^ swz));
#define LDB(NF, KK, BASE)                                                     \
  bF[NF][KK] = *(const short8*)(smem + (BASE) + 32768 +                       \
      ((((wc*32 + (NF)*16 + r) * 128) + ((KK)*32 + ko)*2) ^ swz));

#define MFMA16(QM)                                                            \
  __builtin_amdgcn_s_setprio(1);                                              \
  _Pragma("unroll") for (int mf4 = 0; mf4 < 4; ++mf4)                         \
    _Pragma("unroll") for (int kk = 0; kk < 2; ++kk)                          \
      _Pragma("unroll") for (int nf = 0; nf < 2; ++nf)                        \
        acc[(QM)*4+mf4][nf] = __builtin_amdgcn_mfma_f32_16x16x32_bf16(        \
            aF[mf4][kk], bF[nf][kk], acc[(QM)*4+mf4][nf], 0, 0, 0);           \
  __builtin_amdgcn_s_setprio(0);

#define DS_A(BASE, QM) _Pragma("unroll")                                      \
  for (int mf4 = 0; mf4 < 4; ++mf4) { LDA(mf4,0,BASE,QM) LDA(mf4,1,BASE,QM) }
#define DS_B(BASE) { LDB(0,0,BASE) LDB(0,1,BASE) LDB(1,0,BASE) LDB(1,1,BASE) }

  // ---- prologue: tiles 0,1 fully staged (12 loads; oldest 4 = t0 qm0+B)
  ST_QM0B(0, 0) ST_QM1(0, 0)
  ST_QM0B(49152, 1) ST_QM1(49152, 1)
  WAIT_VM(8) BAR()

  // ---- G(0)
  { DS_A(0,0) DS_B(0)
    WAIT_LGKM() MFMA16(0)
    WAIT_VM(6) BAR() }
  { DS_A(0,1)
    ST_QM0B(0, 2)                 // t2 qm0+B -> buf0 (freed by ph0 barrier)
    WAIT_LGKM() MFMA16(1)
    WAIT_VM(6) BAR() }

  // ---- steady: kt = 1..13
  #pragma unroll 1
  for (int kt = 1; kt <= 13; ++kt) {
    const int bo = (kt & 1) * 49152;
    const int bo2 = bo ^ 49152;
    { DS_A(bo,0) DS_B(bo)
      ST_QM1(bo2, kt+1)           // (kt+1).qm1 -> other buf (qm1 freed @ G(kt-1).ph1)
      WAIT_LGKM() MFMA16(0)
      WAIT_VM(6) BAR() }
    { DS_A(bo,1)
      ST_QM0B(bo, kt+2)           // (kt+2).qm0+B -> this buf (freed @ ph0)
      WAIT_LGKM() MFMA16(1)
      WAIT_VM(6) BAR() }
  }

  // ---- G(14) (buf0)
  { DS_A(0,0) DS_B(0)
    ST_QM1(49152, 15)
    WAIT_LGKM() MFMA16(0)
    WAIT_VM(6) BAR() }
  { DS_A(0,1)
    WAIT_LGKM() MFMA16(1)
    WAIT_VM(2) BAR() }
  // ---- G(15) (buf1)
  { DS_A(49152,0) DS_B(49152)
    WAIT_LGKM() MFMA16(0)
    WAIT_VM(0) BAR() }
  { DS_A(49152,1)
    WAIT_LGKM() MFMA16(1) }

#undef ST_A
#undef ST_B
#undef ST_QM0B
#undef ST_QM1
#undef WAIT_VM
#undef WAIT_LGKM
#undef BAR
#undef LDA
#undef LDB
#undef MFMA16
#undef DS_A
#undef DS_B

  // ---- epilogue: bias + relu, C/D map col=lane&15, row=(lane>>4)*4+reg
  float bn2[2];
  bn2[0] = bias[blockN + wc * 32 + r];
  bn2[1] = bias[blockN + wc * 32 + 16 + r];
  const int rowBase = blockM + wr * 128 + (l >> 4) * 4;
  #pragma unroll
  for (int mf = 0; mf < 8; ++mf)
    #pragma unroll
    for (int j = 0; j < 4; ++j) {
      int grow = rowBase + mf * 16 + j;
      #pragma unroll
      for (int nf = 0; nf < 2; ++nf) {
        float v = acc[mf][nf][j] + bn2[nf];
        v = v > 0.f ? v : 0.f;
        C[(size_t)grow * 1024 + blockN + wc * 32 + nf * 16 + r] = f2bf(v);
      }
    }
}

// ---- m97-structure GEMM (proven) for the final layer (N=512, counts mask, f32 out)
template<int RELU, int FINAL>
__global__ __launch_bounds__(256, 2)
void gemm_kernel(const unsigned short* __restrict__ A, int lda,
                 const unsigned short* __restrict__ Bt, int ldb, int Kext,
                 const float* __restrict__ bias,
                 unsigned short* __restrict__ Cb,
                 float* __restrict__ Cf,
                 const int* __restrict__ counts,
                 int N) {
  __shared__ __align__(16) unsigned short As[128 * 64];
  __shared__ __align__(16) unsigned short Bs[128 * 64];
  const int t = threadIdx.x;
  const int l = t & 63, w = t >> 6;
  const int wr = w >> 1, wc = w & 1;

  const int nwg = gridDim.x * gridDim.y;
  const int wg = blockIdx.y * gridDim.x + blockIdx.x;
  const int swzid = (wg & 7) * (nwg >> 3) + (wg >> 3);
  const int bx = swzid % gridDim.x, by = swzid / gridDim.x;

  const int blockM = by * 128, blockN = bx * 128;
  const unsigned short* Ab = A + (size_t)blockM * lda;
  const unsigned short* Bb = Bt + (size_t)blockN * ldb;

  f32x4 acc[4][4];
  #pragma unroll
  for (int m = 0; m < 4; ++m)
    #pragma unroll
    for (int n = 0; n < 4; ++n) acc[m][n] = (f32x4){0.f, 0.f, 0.f, 0.f};

  int so_row[4], so_col[4];
  #pragma unroll
  for (int c = 0; c < 4; ++c) {
    int o = c * 4096 + t * 16;
    int row = o >> 7;
    int cb = (o & 127) ^ ((row & 7) << 4);
    so_row[c] = row; so_col[c] = cb >> 1;
  }

  const int r = l & 15, ko = (l >> 4) * 8;
  const int swz = (r & 7) << 4;
  const char* Ac = (const char*)As;
  const char* Bc = (const char*)Bs;
  const int NT = Kext >> 6;

  #pragma unroll
  for (int c = 0; c < 4; ++c) {
    gload_lds16(Ab + (size_t)so_row[c] * lda + so_col[c], (char*)As + c * 4096 + w * 1024);
    gload_lds16(Bb + (size_t)so_row[c] * ldb + so_col[c], (char*)Bs + c * 4096 + w * 1024);
  }

  for (int kt = 0; kt < NT; ++kt) {
    __syncthreads();
    #pragma unroll
    for (int kk = 0; kk < 64; kk += 32) {
      short8 aF[4], bF[4];
      #pragma unroll
      for (int m = 0; m < 4; ++m)
        aF[m] = *(const short8*)(Ac + (((wr * 64 + m * 16 + r) * 128 + (kk + ko) * 2) ^ swz));
      #pragma unroll
      for (int n = 0; n < 4; ++n)
        bF[n] = *(const short8*)(Bc + (((wc * 64 + n * 16 + r) * 128 + (kk + ko) * 2) ^ swz));
      #pragma unroll
      for (int m = 0; m < 4; ++m)
        #pragma unroll
        for (int n = 0; n < 4; ++n)
          acc[m][n] = __builtin_amdgcn_mfma_f32_16x16x32_bf16(aF[m], bF[n], acc[m][n], 0, 0, 0);
    }
    __syncthreads();
    if (kt + 1 < NT) {
      int k0 = (kt + 1) << 6;
      #pragma unroll
      for (int c = 0; c < 4; ++c) {
        gload_lds16(Ab + (size_t)so_row[c] * lda + k0 + so_col[c], (char*)As + c * 4096 + w * 1024);
        gload_lds16(Bb + (size_t)so_row[c] * ldb + k0 + so_col[c], (char*)Bs + c * 4096 + w * 1024);
      }
    }
  }

  float bn[4];
  #pragma unroll
  for (int n = 0; n < 4; ++n) bn[n] = bias[blockN + wc * 64 + n * 16 + r];
  const int rowBase = blockM + wr * 64 + (l >> 4) * 4;
  #pragma unroll
  for (int m = 0; m < 4; ++m) {
    #pragma unroll
    for (int jj = 0; jj < 4; ++jj) {
      int grow = rowBase + m * 16 + jj;
      if (FINAL) {
        float cm = (counts[grow] > 0) ? 1.0f : 0.0f;
        #pragma unroll
        for (int n = 0; n < 4; ++n) {
          float v = (acc[m][n][jj] + bn[n]) * cm;
          Cf[(size_t)grow * N + blockN + wc * 64 + n * 16 + r] = v;
        }
      } else {
        #pragma unroll
        for (int n = 0; n < 4; ++n) {
          float v = acc[m][n][jj] + bn[n];
          if (RELU) v = v > 0.f ? v : 0.f;
          Cb[(size_t)grow * N + blockN + wc * 64 + n * 16 + r] = f2bf(v);
        }
      }
    }
  }
}

extern "C" void kernel_launch(void* const* d_in, const int* in_sizes, int n_in,
                              void* d_out, int out_size, void* d_ws, size_t ws_size,
                              hipStream_t stream) {
  const float* a_emb = (const float*)d_in[0];
  const float* b_emb = (const float*)d_in[1];
  const int*   midx  = (const int*)d_in[2];
  const float* W_in  = (const float*)d_in[3];
  const float* b_in  = (const float*)d_in[4];
  const float* W_h   = (const float*)d_in[5];
  const float* b_h   = (const float*)d_in[6];
  const float* W_out = (const float*)d_in[7];
  const float* b_out = (const float*)d_in[8];
  char* ws = (char*)d_ws;

  unsigned short* X      = (unsigned short*)(ws);              // 16 MiB (reused as H2)
  unsigned short* H1     = (unsigned short*)(ws + 16777216);   // 16 MiB
  unsigned short* Wt_in  = (unsigned short*)(ws + 33554432);   //  2 MiB
  unsigned short* Wt_h   = (unsigned short*)(ws + 35651584);   //  2 MiB
  unsigned short* Wt_out = (unsigned short*)(ws + 37748736);   //  1 MiB
  int*            counts = (int*)(ws + 38797312);              // 32 KiB

  (void)hipFuncSetAttribute((const void*)gemm8_kernel,
                            hipFuncAttributeMaxDynamicSharedMemorySize, 98304);

  prep_kernel<<<4608, 256, 0, stream>>>(a_emb, b_emb, midx, W_in, W_h, W_out,
                                        X, counts, Wt_in, Wt_h, Wt_out);

  gemm8_kernel<<<dim3(8, 32), 512, 98304, stream>>>(X,  Wt_in, b_in, H1);
  gemm8_kernel<<<dim3(8, 32), 512, 98304, stream>>>(H1, Wt_h,  b_h,  X);
  gemm_kernel<0, 1><<<dim3(4, 64), 256, 0, stream>>>(X, 1024, Wt_out, 1024, 1024,
                                                     b_out, nullptr, (float*)d_out, counts, 512);
}